// Round 10
// baseline (84.133 us; speedup 1.0000x reference)
//
#include <hip/hip_runtime.h>
#include <hip/hip_bf16.h>

typedef __bf16 bf16x8 __attribute__((ext_vector_type(8)));
typedef float  f32x4  __attribute__((ext_vector_type(4)));

// Async global->LDS DMA (no register result: compiler cannot re-roll/sink it).
__device__ __forceinline__ void dma16(const float* g, float* l) {
    typedef const __attribute__((address_space(1))) unsigned int* gp_t;
    typedef __attribute__((address_space(3))) unsigned int*       lp_t;
    __builtin_amdgcn_global_load_lds((gp_t)(const void*)g, (lp_t)(void*)l, 16, 0, 0);
}

// 512 threads = 8 waves. Block owns cbase in [0,16), ALL 4 sharer column-blocks
// (cbase+16j share identical k-block sets), and 256 M-rows. Outer loop u=0..3
// over the shared k-block rs[u]=rowi[u][cbase]:
//   A tile (256x64 fp32, 64 KB) staged via global_load_lds with pre-swizzled
//   source (round-9 proven: linear dest, XOR (row&15)<<4 on read, 0 conflicts);
//   B tile = 4 sharer blocks (32 KB bf16 [j][n][k], XOR-swizzled) reg-staged,
//   loads issued BEFORE compute of the previous u (T14 issue-early).
// Each A fragment feeds 16 column-fragments (4 sharers x 4) -> A read ONCE
// from cache: A traffic 512->128 MB. That was round 9's limiter (768 MB through
// L2/L3 at 13.1 TB/s = saturation); now ~384 MB total.
__global__ __launch_bounds__(512, 2) void sparse_linear_kernel(
    const float* __restrict__ A, const float* __restrict__ Bd,
    const int* __restrict__ rowi, const int* __restrict__ di,
    float* __restrict__ C)
{
    __shared__ __align__(16) float At[256 * 64];              // 64 KB fp32, swizzled
    __shared__ __align__(16) unsigned short Bt[4 * 64 * 64];  // 32 KB bf16 [j][n][k]
    char* AtB = (char*)At;
    char* BtB = (char*)Bt;

    const int bid   = blockIdx.x;
    const int cbase = bid & 15;        // same-cbase blocks: bid%8 const -> same XCD (B L2-resident)
    const int mgrp  = bid >> 4;        // 0..31 -> rows [mgrp*256, +256)
    const int t     = threadIdx.x;
    const int lane  = t & 63;
    const int w     = t >> 6;          // 0..7

    int rs[4], dsl[4][4];
    #pragma unroll
    for (int u = 0; u < 4; ++u) {
        rs[u] = rowi[u * 64 + cbase];              // shared k-block of all 4 sharers
        #pragma unroll
        for (int j = 0; j < 4; ++j)
            dsl[u][j] = di[u * 64 + cbase + 16 * j];
    }

    // B stager roles (fixed per thread): sharer sb, k-half kh, column n
    const int sb = t >> 7;             // 0..3
    const int kh_s = (t >> 6) & 1;     // 0..1
    const int n_s  = t & 63;

    // ---- A DMA stage for k-block u: wave w fills local rows [w*32, w*32+32) ----
    // Instr i covers 4 rows; lane l -> row i*4+(l>>4), 16B slot (l&15). Global
    // source pre-swizzled so the read-side XOR (row&15)<<4 sees linear data.
    auto dmaA = [&](int u) {
        #pragma unroll
        for (int i = 0; i < 8; ++i) {
            const int lr  = w * 32 + i * 4 + (lane >> 4);          // local row
            const int kfl = (((lane & 15) * 16) ^ ((lr & 15) << 4)) >> 2;
            const float* g = A + (long)(mgrp * 256 + lr) * 4096 + rs[u] * 64 + kfl;
            dma16(g, At + (w * 32 + i * 4) * 64);
        }
    };

    float bv[32];
    auto loadB = [&](int u) {
        const float* Bg = Bd + (long)dsl[u][sb] * 64 + (long)kh_s * 32 * 16384 + n_s;
        #pragma unroll
        for (int k = 0; k < 32; ++k) bv[k] = Bg[(long)k * 16384];
    };
    auto writeB = [&]() {
        char* dst = BtB + sb * 8192 + n_s * 128;
        const int sw = (n_s & 7) << 4;
        #pragma unroll
        for (int k4 = 0; k4 < 8; ++k4) {
            union { ushort4 u4; __bf16 e[4]; } pk;
            pk.e[0] = (__bf16)bv[4 * k4 + 0];
            pk.e[1] = (__bf16)bv[4 * k4 + 1];
            pk.e[2] = (__bf16)bv[4 * k4 + 2];
            pk.e[3] = (__bf16)bv[4 * k4 + 3];
            *(ushort4*)(dst + ((kh_s * 64 + 8 * k4) ^ sw)) = pk.u4;
        }
    };

    f32x4 acc[2][16];   // [mt][j*4+n2] = 128 VGPR
    #pragma unroll
    for (int m = 0; m < 2; ++m)
        #pragma unroll
        for (int q = 0; q < 16; ++q) acc[m][q] = f32x4{0.f, 0.f, 0.f, 0.f};

    // ---- prologue: stage u=0 ----
    loadB(0);
    dmaA(0);
    writeB();
    __syncthreads();   // drains DMA vmcnt + ds writes; tiles ready

    #pragma unroll
    for (int u = 0; u < 4; ++u) {
        if (u < 3) loadB(u + 1);   // 32 regs in flight across compute (T14)

        // ---- compute u ----
        bf16x8 af[2][2];
        #pragma unroll
        for (int mt = 0; mt < 2; ++mt) {
            const char* arow = AtB + (w * 32 + mt * 16 + (lane & 15)) * 256;
            const int key = (lane & 15) << 4;
            #pragma unroll
            for (int kh = 0; kh < 2; ++kh) {
                f32x4 x0 = *(const f32x4*)(arow + ((kh * 128 + (lane >> 4) * 32) ^ key));
                f32x4 x1 = *(const f32x4*)(arow + ((kh * 128 + (lane >> 4) * 32 + 16) ^ key));
                union { bf16x8 v; __bf16 e[8]; } a;
                #pragma unroll
                for (int i = 0; i < 4; ++i) {
                    a.e[i]     = (__bf16)x0[i];
                    a.e[i + 4] = (__bf16)x1[i];
                }
                af[mt][kh] = a.v;
            }
        }
        #pragma unroll
        for (int kh = 0; kh < 2; ++kh)
            #pragma unroll
            for (int j = 0; j < 4; ++j) {
                const char* bb = BtB + j * 8192;
                #pragma unroll
                for (int n2 = 0; n2 < 4; ++n2) {
                    const int nr = n2 * 16 + (lane & 15);
                    bf16x8 bf = *(const bf16x8*)(bb + nr * 128 +
                                ((kh * 64 + (lane >> 4) * 16) ^ ((nr & 7) << 4)));
                    acc[0][j * 4 + n2] = __builtin_amdgcn_mfma_f32_16x16x32_bf16(
                        af[0][kh], bf, acc[0][j * 4 + n2], 0, 0, 0);
                    acc[1][j * 4 + n2] = __builtin_amdgcn_mfma_f32_16x16x32_bf16(
                        af[1][kh], bf, acc[1][j * 4 + n2], 0, 0, 0);
                }
            }

        __syncthreads();   // all waves done reading At/Bt (Bloads drained too - already landed)

        if (u < 3) {
            dmaA(u + 1);       // overwrite At (safe: post-barrier)
            writeB();          // overwrite Bt from pre-issued loads
            __syncthreads();   // drains DMA + ds writes; next tiles ready
        }
    }

    // ---- epilogue: C stores (NT: keep A/B resident in caches) ----
    #pragma unroll
    for (int mt = 0; mt < 2; ++mt) {
        const long crow0 = (long)mgrp * 256 + w * 32 + mt * 16 + (lane >> 4) * 4;
        #pragma unroll
        for (int j = 0; j < 4; ++j) {
            const long col0 = (long)(cbase + 16 * j) * 64 + (lane & 15);
            #pragma unroll
            for (int n2 = 0; n2 < 4; ++n2)
                #pragma unroll
                for (int v = 0; v < 4; ++v)
                    __builtin_nontemporal_store(acc[mt][j * 4 + n2][v],
                        &C[(crow0 + v) * 4096 + col0 + n2 * 16]);
        }
    }
}

extern "C" void kernel_launch(void* const* d_in, const int* in_sizes, int n_in,
                              void* d_out, int out_size, void* d_ws, size_t ws_size,
                              hipStream_t stream) {
    const float* A    = (const float*)d_in[0];
    const float* Bd   = (const float*)d_in[1];
    const int*   rowi = (const int*)d_in[2];
    const int*   di   = (const int*)d_in[3];
    float*       C    = (float*)d_out;

    dim3 grid(16 * 32);   // 16 cbases x 32 mgrps = 512 blocks (2 generations/CU)
    dim3 block(512);
    hipLaunchKernelGGL(sparse_linear_kernel, grid, block, 0, stream,
                       A, Bd, rowi, di, C);
}

// Round 11
// 56.251 us; speedup vs baseline: 1.4957x; 1.4957x over previous
//
#include <hip/hip_runtime.h>
#include <hip/hip_bf16.h>

typedef __bf16 bf16x8 __attribute__((ext_vector_type(8)));
typedef float  f32x4  __attribute__((ext_vector_type(4)));

// Async global->LDS DMA (no register result: compiler cannot re-roll/sink it).
__device__ __forceinline__ void dma16(const float* g, float* l) {
    typedef const __attribute__((address_space(1))) unsigned int* gp_t;
    typedef __attribute__((address_space(3))) unsigned int*       lp_t;
    __builtin_amdgcn_global_load_lds((gp_t)(const void*)g, (lp_t)(void*)l, 16, 0, 0);
}

// PERSISTENT round-9 structure: 512 blocks (64 c x 8 row-groups) = 2/CU, ONE
// residency generation, zero tail. Each block: 4 waves, one column-block c,
// 1024 M-rows as 4 chunks x 256 rows = 64 continuous pipeline steps.
// B (4 nonzero 64x64 blocks of col c) staged ONCE per block (was 4x in r9).
// A: per-WAVE private 3-slot LDS ring (16x64 fp32/slot), global_load_lds with
// pre-swizzled source (linear dest, XOR r<<4 on read; 0 conflicts, r9-proven).
// No barriers in the 64-step main loop; sync = counted vmcnt, never 0 mid-loop.
// C stores issue at each chunk boundary and drain under the next chunk's
// compute. Stores enter the vmcnt queue: retirement is in-order, so boundary
// steps (local 0..2) use vmcnt(24) = 8 younger loads + 16 younger stores;
// all other steps vmcnt(8). Refill EVERY step (tail-clamped addresses) keeps
// the wait schedule uniform.
__global__ __launch_bounds__(256, 2) void sparse_linear_kernel(
    const float* __restrict__ A, const float* __restrict__ Bd,
    const int* __restrict__ rowi, const int* __restrict__ di,
    float* __restrict__ C)
{
    __shared__ __align__(16) float Aring[4][3][16 * 64];       // 48 KB
    __shared__ __align__(16) unsigned short Bt[4 * 64 * 64];   // 32 KB
    char* BtB = (char*)Bt;

    const int bid = blockIdx.x;
    const int c   = bid & 63;          // sharers c,c+16j: bid diff 16 -> same XCD (L2 A-reuse)
    const int grp = bid >> 6;          // 0..7 -> rows [grp*1024, +1024)
    const int t    = threadIdx.x;
    const int lane = t & 63;
    const int w    = t >> 6;           // 0..3

    int rs[4], ds[4];
    #pragma unroll
    for (int s = 0; s < 4; ++s) {
        rs[s] = rowi[s * 64 + c];
        ds[s] = di[s * 64 + c];
    }
    int koff[4];
    #pragma unroll
    for (int s = 0; s < 4; ++s) koff[s] = rs[s] * 64;

    const long wrow0 = (long)grp * 1024 + w * 64;   // + q*256 + mt*16

    // DMA one 16x64 step-tile (chunk q, k-block kb, m-tile mt) into ring slot.
    // Instr i covers rows i*4+(lane>>4); source pre-swizzled (XOR rr<<4).
    auto dmaA = [&](int q, int kb, int mt, int slot) {
        float* slotp = &Aring[w][slot][0];
        #pragma unroll
        for (int i = 0; i < 4; ++i) {
            const int rr  = i * 4 + (lane >> 4);
            const int kfl = (((lane & 15) * 16) ^ (rr << 4)) >> 2;
            const float* g = A + (wrow0 + q * 256 + mt * 16 + rr) * 4096 + koff[kb] + kfl;
            dma16(g, slotp + i * 256);
        }
    };

    // ---- prologue: fill slots 0..2 = steps 0..2 (q=0, kb=0, mt=0,1,2) ----
    dmaA(0, 0, 0, 0);
    dmaA(0, 0, 1, 1);
    dmaA(0, 0, 2, 2);

    // ---- stage B once: wave sb stages block sb; lane n owns column n ----
    {
        const int n  = t & 63;
        const int sb = t >> 6;
        const float* Bg = Bd + (long)ds[sb] * 64 + n;   // row stride = BN*TB = 16384
        char* dst = BtB + sb * 8192 + n * 128;
        const int sw = (n & 7) << 4;
        #pragma unroll
        for (int k4 = 0; k4 < 16; ++k4) {
            union { ushort4 u4; __bf16 e[4]; } pk;
            pk.e[0] = (__bf16)Bg[(long)(4 * k4 + 0) * 16384];
            pk.e[1] = (__bf16)Bg[(long)(4 * k4 + 1) * 16384];
            pk.e[2] = (__bf16)Bg[(long)(4 * k4 + 2) * 16384];
            pk.e[3] = (__bf16)Bg[(long)(4 * k4 + 3) * 16384];
            *(ushort4*)(dst + ((8 * k4) ^ sw)) = pk.u4;
        }
    }
    __syncthreads();   // the only barrier (drains prologue DMAs + B writes)

    f32x4 acc[4][4];   // [mt][n2] for the current chunk
    #pragma unroll
    for (int m = 0; m < 4; ++m)
        #pragma unroll
        for (int n2 = 0; n2 < 4; ++n2) acc[m][n2] = f32x4{0.f, 0.f, 0.f, 0.f};

    bf16x8 bfr[2][4];  // B fragments of current kb, register-held 4 steps

    #pragma unroll 1
    for (int q = 0; q < 4; ++q) {
        const int qm3 = q % 3;   // slot base: (16q+local)%3 = (q+local)%3

        #pragma unroll
        for (int local = 0; local < 16; ++local) {
            const int kb = local >> 2, mt = local & 3;
            int slot = qm3 + (local % 3);
            if (slot >= 3) slot -= 3;

            // Counted wait (in-order retirement): boundary-adjacent steps see
            // 16 younger stores + 8 younger load-groups -> 24; else 8.
            if (local < 3) asm volatile("s_waitcnt vmcnt(24)" ::: "memory");
            else           asm volatile("s_waitcnt vmcnt(8)"  ::: "memory");
            __builtin_amdgcn_sched_barrier(0);

            // B fragments: refresh once per kb (register-held across 4 steps)
            if (mt == 0) {
                const char* bbase = BtB + kb * 8192;
                #pragma unroll
                for (int kh = 0; kh < 2; ++kh)
                    #pragma unroll
                    for (int n2 = 0; n2 < 4; ++n2) {
                        const int nr = n2 * 16 + (lane & 15);
                        const int kbyte = kh * 64 + (lane >> 4) * 16;
                        bfr[kh][n2] = *(const bf16x8*)(bbase + nr * 128 + (kbyte ^ ((nr & 7) << 4)));
                    }
            }

            // A fragment: swizzled read from ring slot; convert fp32->bf16
            const char* ab = (const char*)&Aring[w][slot][0];
            const int r   = lane & 15;
            const int q32 = (lane >> 4) * 32;
            f32x4 a0 = *(const f32x4*)(ab + r * 256 + ((q32)            ^ (r << 4)));
            f32x4 a1 = *(const f32x4*)(ab + r * 256 + ((q32 + 16)       ^ (r << 4)));
            f32x4 a2 = *(const f32x4*)(ab + r * 256 + ((128 + q32)      ^ (r << 4)));
            f32x4 a3 = *(const f32x4*)(ab + r * 256 + ((128 + q32 + 16) ^ (r << 4)));
            union { bf16x8 v; __bf16 e[8]; } af0, af1;
            #pragma unroll
            for (int i = 0; i < 4; ++i) {
                af0.e[i]     = (__bf16)a0[i];
                af0.e[i + 4] = (__bf16)a1[i];
                af1.e[i]     = (__bf16)a2[i];
                af1.e[i + 4] = (__bf16)a3[i];
            }

            // 8 MFMAs for this (kb, mt)
            __builtin_amdgcn_s_setprio(1);
            #pragma unroll
            for (int kh = 0; kh < 2; ++kh) {
                const bf16x8 afv = kh ? af1.v : af0.v;
                #pragma unroll
                for (int n2 = 0; n2 < 4; ++n2)
                    acc[mt][n2] = __builtin_amdgcn_mfma_f32_16x16x32_bf16(afv, bfr[kh][n2], acc[mt][n2], 0, 0, 0);
            }
            __builtin_amdgcn_s_setprio(0);

            // Refill this slot for step+3 (every step; tail addresses clamped
            // to valid rows so the wait schedule stays uniform).
            {
                int l2 = local + 3, q2 = q;
                if (l2 >= 16) { l2 -= 16; ++q2; }
                if (q2 > 3) q2 = 3;                 // harmless redundant DMA at tail
                dmaA(q2, l2 >> 2, l2 & 3, slot);
            }

            // Chunk boundary: store this chunk's C (drains under next chunk).
            if (local == 15) {
                __builtin_amdgcn_sched_barrier(0);
                #pragma unroll
                for (int mts = 0; mts < 4; ++mts) {
                    const long crow0 = wrow0 + q * 256 + mts * 16 + (lane >> 4) * 4;
                    const long col0  = (long)c * 64 + (lane & 15);
                    #pragma unroll
                    for (int n2 = 0; n2 < 4; ++n2) {
                        #pragma unroll
                        for (int v = 0; v < 4; ++v)
                            __builtin_nontemporal_store(acc[mts][n2][v],
                                &C[(crow0 + v) * 4096 + col0 + n2 * 16]);
                        acc[mts][n2] = f32x4{0.f, 0.f, 0.f, 0.f};
                    }
                }
                __builtin_amdgcn_sched_barrier(0);
            }
        }
    }

    asm volatile("s_waitcnt vmcnt(0)" ::: "memory");   // drain tail DMAs/stores
}

extern "C" void kernel_launch(void* const* d_in, const int* in_sizes, int n_in,
                              void* d_out, int out_size, void* d_ws, size_t ws_size,
                              hipStream_t stream) {
    const float* A    = (const float*)d_in[0];
    const float* Bd   = (const float*)d_in[1];
    const int*   rowi = (const int*)d_in[2];
    const int*   di   = (const int*)d_in[3];
    float*       C    = (float*)d_out;

    dim3 grid(8 * 64);    // 8 row-groups x 64 columns = 512 blocks = 2/CU, 1 generation
    dim3 block(256);
    hipLaunchKernelGGL(sparse_linear_kernel, grid, block, 0, stream,
                       A, Bd, rowi, di, C);
}